// Round 3
// baseline (123.989 us; speedup 1.0000x reference)
//
#include <hip/hip_runtime.h>
#include <math.h>

#define NCLUS 64
#define BLOCK 256

#if __has_builtin(__builtin_amdgcn_exp2f)
#define EXP2F(x) __builtin_amdgcn_exp2f(x)
#else
#define EXP2F(x) __expf(0.6931471805599453f * (x))
#endif

// softplus(p) on [0,1] ~= C0 + p*(C1 + p*(C2 + p*(C3 + p*C4))), err ~2e-6.
// C0 is hoisted out of the inner loop and added in finalize as n*64*C0.
#define SP_C0 0.69314718
#define SP_C1 0.49991956f
#define SP_C2 0.12562243f
#define SP_C3 -0.00152320f
#define SP_C4 -0.00390297f

// ws layout (floats):
//  [0,64)    counts
//  [64,256)  coord sums [c*3+d]
//  [256,320) margin sums
//  [320,576) params4 [c*4]: ax, ay, az, b   (arg = ax*x+ay*y+az*z+w2*es+b)
//  [576,640) w2[c] = -log2(e)/(2*sigma^2)
//  [640,704) sigma[c]
// doubles at f+704: acc[0]=bce(-C0-part), acc[1]=seed, acc[2]=smooth

__global__ void init_ws_kernel(float* f) {
    int i = blockIdx.x * blockDim.x + threadIdx.x;
    if (i < 320) f[i] = 0.0f;
    if (i < 3) ((double*)(f + 704))[i] = 0.0;
}

__global__ __launch_bounds__(BLOCK) void cluster_sums_kernel(
        const float* __restrict__ coords, const float* __restrict__ margins,
        const int* __restrict__ labels, int n, float* __restrict__ f) {
    // 8 replicas indexed by lane&7; row padded to 65 so bank = (rep*5+field+c)%32
    __shared__ float s_h[8][5][65];
    for (int i = threadIdx.x; i < 8 * 5 * 65; i += blockDim.x)
        ((float*)s_h)[i] = 0.0f;
    __syncthreads();

    const int rep = threadIdx.x & 7;
    const int chunks = n >> 2;
    const int stride = gridDim.x * blockDim.x;
    const float4* c4 = (const float4*)coords;
    const float4* m4 = (const float4*)margins;
    const int4* l4 = (const int4*)labels;

    for (int ch = blockIdx.x * blockDim.x + threadIdx.x; ch < chunks; ch += stride) {
        float4 e0 = c4[ch * 3 + 0], e1 = c4[ch * 3 + 1], e2 = c4[ch * 3 + 2];
        float4 mg = m4[ch];
        int4 lb = l4[ch];
        float x[4] = {e0.x, e0.w, e1.z, e2.y};
        float y[4] = {e0.y, e1.x, e1.w, e2.z};
        float z[4] = {e0.z, e1.y, e2.x, e2.w};
        float m[4] = {mg.x, mg.y, mg.z, mg.w};
        int   l[4] = {lb.x, lb.y, lb.z, lb.w};
#pragma unroll
        for (int k = 0; k < 4; ++k) {
            atomicAdd(&s_h[rep][0][l[k]], 1.0f);
            atomicAdd(&s_h[rep][1][l[k]], x[k]);
            atomicAdd(&s_h[rep][2][l[k]], y[k]);
            atomicAdd(&s_h[rep][3][l[k]], z[k]);
            atomicAdd(&s_h[rep][4][l[k]], m[k]);
        }
    }

    int rem = n & 3;
    int gid = blockIdx.x * blockDim.x + threadIdx.x;
    if (gid < rem) {
        int i = (chunks << 2) + gid;
        int lab = labels[i];
        atomicAdd(&s_h[rep][0][lab], 1.0f);
        atomicAdd(&s_h[rep][1][lab], coords[i * 3 + 0]);
        atomicAdd(&s_h[rep][2][lab], coords[i * 3 + 1]);
        atomicAdd(&s_h[rep][3][lab], coords[i * 3 + 2]);
        atomicAdd(&s_h[rep][4][lab], margins[i]);
    }
    __syncthreads();

    for (int idx = threadIdx.x; idx < 5 * NCLUS; idx += blockDim.x) {
        int field = idx >> 6, c = idx & 63;
        float v = 0.0f;
#pragma unroll
        for (int r = 0; r < 8; ++r) v += s_h[r][field][c];
        int dest = (field == 0) ? c : (field <= 3 ? 64 + c * 3 + (field - 1) : 256 + c);
        atomicAdd(&f[dest], v);
    }
}

__global__ void compute_params_kernel(float* f) {
    int c = threadIdx.x;
    if (c < NCLUS) {
        float inv = 1.0f / f[c];
        float sigma = f[256 + c] * inv;
        float cx = f[64 + c * 3 + 0] * inv;
        float cy = f[64 + c * 3 + 1] * inv;
        float cz = f[64 + c * 3 + 2] * inv;
        float w2 = -1.4426950408889634f / (2.0f * sigma * sigma);
        f[320 + c * 4 + 0] = -2.0f * w2 * cx;
        f[320 + c * 4 + 1] = -2.0f * w2 * cy;
        f[320 + c * 4 + 2] = -2.0f * w2 * cz;
        f[320 + c * 4 + 3] = w2 * (cx * cx + cy * cy + cz * cz);
        f[576 + c] = w2;
        f[640 + c] = sigma;
    }
}

__device__ __forceinline__ float block_reduce_sum(float v, float* s_red) {
    for (int o = 32; o > 0; o >>= 1) v += __shfl_down(v, o);
    int lane = threadIdx.x & 63, wid = threadIdx.x >> 6;
    __syncthreads();
    if (lane == 0) s_red[wid] = v;
    __syncthreads();
    float t = 0.0f;
    if (threadIdx.x == 0)
        for (int w = 0; w < BLOCK / 64; ++w) t += s_red[w];
    return t;  // valid on thread 0 only
}

__global__ __launch_bounds__(BLOCK) void main_loss_kernel(
        const float* __restrict__ emb, const float* __restrict__ margins,
        const float* __restrict__ seed, const int* __restrict__ labels,
        int n, const float* __restrict__ f, double* __restrict__ acc) {
    __shared__ float4 s_par[NCLUS];  // ax,ay,az,b
    __shared__ float s_w[NCLUS];
    __shared__ float s_sig[NCLUS];
    __shared__ float s_red[BLOCK / 64];

    if (threadIdx.x < NCLUS) {
        s_par[threadIdx.x] = ((const float4*)(f + 320))[threadIdx.x];
        s_w[threadIdx.x] = f[576 + threadIdx.x];
        s_sig[threadIdx.x] = f[640 + threadIdx.x];
    }
    __syncthreads();

    const int chunks = n >> 2;
    const int npairs = chunks >> 1;      // 8 points per pair
    const int stride = gridDim.x * blockDim.x;
    const float4* e4 = (const float4*)emb;
    const float4* m4 = (const float4*)margins;
    const float4* s4 = (const float4*)seed;
    const int4* l4 = (const int4*)labels;

    float bce = 0.0f, seed_s = 0.0f, smooth_s = 0.0f;

    for (int pi = blockIdx.x * blockDim.x + threadIdx.x; pi < npairs; pi += stride) {
        int ch0 = pi * 2;
        float x[8], y[8], z[8], es[8], a[8];
#pragma unroll
        for (int h = 0; h < 2; ++h) {
            float4 e0 = e4[(ch0 + h) * 3 + 0];
            float4 e1 = e4[(ch0 + h) * 3 + 1];
            float4 e2 = e4[(ch0 + h) * 3 + 2];
            x[h * 4 + 0] = e0.x; y[h * 4 + 0] = e0.y; z[h * 4 + 0] = e0.z;
            x[h * 4 + 1] = e0.w; y[h * 4 + 1] = e1.x; z[h * 4 + 1] = e1.y;
            x[h * 4 + 2] = e1.z; y[h * 4 + 2] = e1.w; z[h * 4 + 2] = e2.x;
            x[h * 4 + 3] = e2.y; y[h * 4 + 3] = e2.z; z[h * 4 + 3] = e2.w;
        }
#pragma unroll
        for (int k = 0; k < 8; ++k) {
            es[k] = fmaf(x[k], x[k], fmaf(y[k], y[k], z[k] * z[k]));
            a[k] = 0.0f;
        }

#pragma unroll 4
        for (int c = 0; c < NCLUS; ++c) {
            float4 pr = s_par[c];
            float w2 = s_w[c];
#pragma unroll
            for (int k = 0; k < 8; ++k) {
                float t = fmaf(pr.x, x[k],
                          fmaf(pr.y, y[k],
                          fmaf(pr.z, z[k],
                          fmaf(w2, es[k], pr.w))));
                float p = EXP2F(t);
                float X = fmaf(p, fmaf(p, fmaf(p, SP_C4, SP_C3), SP_C2), SP_C1);
                a[k] = fmaf(p, X, a[k]);
            }
        }
        bce += ((a[0] + a[1]) + (a[2] + a[3])) + ((a[4] + a[5]) + (a[6] + a[7]));

        float4 mg0 = m4[ch0], mg1 = m4[ch0 + 1];
        float4 sd0 = s4[ch0], sd1 = s4[ch0 + 1];
        int4 lb0 = l4[ch0], lb1 = l4[ch0 + 1];
        float m[8] = {mg0.x, mg0.y, mg0.z, mg0.w, mg1.x, mg1.y, mg1.z, mg1.w};
        float s[8] = {sd0.x, sd0.y, sd0.z, sd0.w, sd1.x, sd1.y, sd1.z, sd1.w};
        int   l[8] = {lb0.x, lb0.y, lb0.z, lb0.w, lb1.x, lb1.y, lb1.z, lb1.w};
#pragma unroll
        for (int k = 0; k < 8; ++k) {
            float4 pr = s_par[l[k]];
            float w2 = s_w[l[k]];
            float t = fmaf(pr.x, x[k],
                      fmaf(pr.y, y[k],
                      fmaf(pr.z, z[k],
                      fmaf(w2, es[k], pr.w))));
            float p = EXP2F(t);
            bce -= p;
            seed_s += fabsf(p - s[k]);
            float dsg = m[k] - s_sig[l[k]];
            smooth_s += dsg * dsg;
        }
    }

    // scalar tail: points not covered by pairs
    int covered = npairs * 8;
    int rem = n - covered;
    int gid = blockIdx.x * blockDim.x + threadIdx.x;
    if (gid < rem) {
        int i = covered + gid;
        float ex = emb[i * 3 + 0], ey = emb[i * 3 + 1], ez = emb[i * 3 + 2];
        float esq = fmaf(ex, ex, fmaf(ey, ey, ez * ez));
        int lab = labels[i];
        float pl = 0.0f;
        for (int c = 0; c < NCLUS; ++c) {
            float4 pr = s_par[c];
            float w2 = s_w[c];
            float t = fmaf(pr.x, ex, fmaf(pr.y, ey, fmaf(pr.z, ez, fmaf(w2, esq, pr.w))));
            float p = EXP2F(t);
            float X = fmaf(p, fmaf(p, fmaf(p, SP_C4, SP_C3), SP_C2), SP_C1);
            bce = fmaf(p, X, bce);
            if (c == lab) pl = p;
        }
        bce -= pl;
        seed_s += fabsf(pl - seed[i]);
        float dsg = margins[i] - s_sig[lab];
        smooth_s += dsg * dsg;
    }

    float r;
    r = block_reduce_sum(bce, s_red);
    if (threadIdx.x == 0) atomicAdd(&acc[0], (double)r);
    r = block_reduce_sum(seed_s, s_red);
    if (threadIdx.x == 0) atomicAdd(&acc[1], (double)r);
    r = block_reduce_sum(smooth_s, s_red);
    if (threadIdx.x == 0) atomicAdd(&acc[2], (double)r);
}

__global__ void finalize_kernel(const double* __restrict__ acc,
                                float* __restrict__ out, int n) {
    // add back the hoisted softplus constant: n * 64 * C0
    double bce_total = acc[0] + (double)n * 64.0 * SP_C0;
    double mask_loss = bce_total / ((double)NCLUS * (double)n);
    double seed_loss = acc[1] / (double)n;
    double smooth_loss = acc[2] / (double)NCLUS;
    out[0] = (float)(mask_loss + seed_loss + smooth_loss);
}

extern "C" void kernel_launch(void* const* d_in, const int* in_sizes, int n_in,
                              void* d_out, int out_size, void* d_ws, size_t ws_size,
                              hipStream_t stream) {
    const float* emb     = (const float*)d_in[0];
    const float* margins = (const float*)d_in[1];
    const float* seed    = (const float*)d_in[2];
    const float* coords  = (const float*)d_in[3];
    const int*   labels  = (const int*)d_in[4];
    int n = in_sizes[4];

    float* f = (float*)d_ws;
    double* acc = (double*)(f + 704);
    float* out = (float*)d_out;

    init_ws_kernel<<<1, 512, 0, stream>>>(f);

    int chunks = n >> 2;
    int grid_sums = (chunks + BLOCK - 1) / BLOCK;
    if (grid_sums < 1) grid_sums = 1;
    if (grid_sums > 1024) grid_sums = 1024;
    cluster_sums_kernel<<<grid_sums, BLOCK, 0, stream>>>(coords, margins, labels, n, f);

    compute_params_kernel<<<1, 64, 0, stream>>>(f);

    int npairs = chunks >> 1;
    int grid_main = (npairs + BLOCK - 1) / BLOCK;
    if (grid_main < 1) grid_main = 1;
    if (grid_main > 2048) grid_main = 2048;
    main_loss_kernel<<<grid_main, BLOCK, 0, stream>>>(emb, margins, seed, labels, n, f, acc);

    finalize_kernel<<<1, 1, 0, stream>>>(acc, out, n);
}

// Round 4
// 64.341 us; speedup vs baseline: 1.9271x; 1.9271x over previous
//
#include <hip/hip_runtime.h>
#include <math.h>

#define NCLUS 64
#define BLOCK 256
#define GC 512              // cluster_sums grid (2 blocks/CU)
#define GM 512              // main_loss grid    (2 blocks/CU); finalize assumes 64*8
#define FP_SCALE 1048576.0f // 2^20 fixed-point scale for cluster sums

#if __has_builtin(__builtin_amdgcn_exp2f)
#define EXP2F(x) __builtin_amdgcn_exp2f(x)
#else
#define EXP2F(x) __expf(0.6931471805599453f * (x))
#endif

// softplus(p) on [0,1] ~= C0 + p*(C1 + p*(C2 + p*(C3 + p*C4))), err ~2e-6.
// C0 hoisted out of the inner loop; added back in finalize as n*64*C0.
#define SP_C0 0.69314718
#define SP_C1 0.49991956f
#define SP_C2 0.12562243f
#define SP_C3 -0.00152320f
#define SP_C4 -0.00390297f

// ws layout:
//  bytes [0, 2560):      u64 S[320]   fixed-point cluster sums, i = field*64+c,
//                        field: 0=count 1=sx 2=sy 3=sz 4=margin
//  bytes [2560, 4096):   float P[384] params: [0,256) float4(ax,ay,az,b) per c,
//                        [256,320) w2[c], [320,384) sigma[c]
//  bytes [4096, 4096+GM*12): float pb[GM*3]  per-block partials (bce,seed,smooth)

__global__ void init_ws_kernel(unsigned long long* S) {
    int i = blockIdx.x * blockDim.x + threadIdx.x;
    if (i < 5 * NCLUS) S[i] = 0ULL;
}

__global__ __launch_bounds__(BLOCK) void cluster_sums_kernel(
        const float* __restrict__ coords, const float* __restrict__ margins,
        const int* __restrict__ labels, int n, unsigned long long* __restrict__ S) {
    // 8 LDS replicas indexed by lane&7; padded to 65 so banks spread
    __shared__ float s_h[8][5][65];
    for (int i = threadIdx.x; i < 8 * 5 * 65; i += blockDim.x)
        ((float*)s_h)[i] = 0.0f;
    __syncthreads();

    const int rep = threadIdx.x & 7;
    const int chunks = n >> 2;
    const int stride = gridDim.x * blockDim.x;
    const float4* c4 = (const float4*)coords;
    const float4* m4 = (const float4*)margins;
    const int4* l4 = (const int4*)labels;

    for (int ch = blockIdx.x * blockDim.x + threadIdx.x; ch < chunks; ch += stride) {
        float4 e0 = c4[ch * 3 + 0], e1 = c4[ch * 3 + 1], e2 = c4[ch * 3 + 2];
        float4 mg = m4[ch];
        int4 lb = l4[ch];
        float x[4] = {e0.x, e0.w, e1.z, e2.y};
        float y[4] = {e0.y, e1.x, e1.w, e2.z};
        float z[4] = {e0.z, e1.y, e2.x, e2.w};
        float m[4] = {mg.x, mg.y, mg.z, mg.w};
        int   l[4] = {lb.x, lb.y, lb.z, lb.w};
#pragma unroll
        for (int k = 0; k < 4; ++k) {
            atomicAdd(&s_h[rep][0][l[k]], 1.0f);
            atomicAdd(&s_h[rep][1][l[k]], x[k]);
            atomicAdd(&s_h[rep][2][l[k]], y[k]);
            atomicAdd(&s_h[rep][3][l[k]], z[k]);
            atomicAdd(&s_h[rep][4][l[k]], m[k]);
        }
    }

    int rem = n & 3;
    int gid = blockIdx.x * blockDim.x + threadIdx.x;
    if (gid < rem) {
        int i = (chunks << 2) + gid;
        int lab = labels[i];
        atomicAdd(&s_h[rep][0][lab], 1.0f);
        atomicAdd(&s_h[rep][1][lab], coords[i * 3 + 0]);
        atomicAdd(&s_h[rep][2][lab], coords[i * 3 + 1]);
        atomicAdd(&s_h[rep][3][lab], coords[i * 3 + 2]);
        atomicAdd(&s_h[rep][4][lab], margins[i]);
    }
    __syncthreads();

    // flush: fixed-point u64 atomics (native integer atomic, fire-and-forget)
    for (int idx = threadIdx.x; idx < 5 * NCLUS; idx += blockDim.x) {
        int field = idx >> 6, c = idx & 63;
        float v = 0.0f;
#pragma unroll
        for (int r = 0; r < 8; ++r) v += s_h[r][field][c];
        unsigned long long q = (unsigned long long)llrintf(v * FP_SCALE);
        if (q) atomicAdd(&S[idx], q);
    }
}

__global__ void compute_params_kernel(const unsigned long long* __restrict__ S,
                                      float* __restrict__ P) {
    int c = threadIdx.x;
    if (c < NCLUS) {
        const double inv_sc = 1.0 / (double)FP_SCALE;
        double cnt = (double)(long long)S[c] * inv_sc;
        double sx  = (double)(long long)S[64 + c] * inv_sc;
        double sy  = (double)(long long)S[128 + c] * inv_sc;
        double sz  = (double)(long long)S[192 + c] * inv_sc;
        double sm  = (double)(long long)S[256 + c] * inv_sc;
        double inv = 1.0 / cnt;
        double sigma = sm * inv;
        double cx = sx * inv, cy = sy * inv, cz = sz * inv;
        double w2 = -1.4426950408889634 / (2.0 * sigma * sigma);
        P[c * 4 + 0] = (float)(-2.0 * w2 * cx);
        P[c * 4 + 1] = (float)(-2.0 * w2 * cy);
        P[c * 4 + 2] = (float)(-2.0 * w2 * cz);
        P[c * 4 + 3] = (float)(w2 * (cx * cx + cy * cy + cz * cz));
        P[256 + c] = (float)w2;
        P[320 + c] = (float)sigma;
    }
}

__device__ __forceinline__ float block_reduce_sum(float v, float* s_red) {
    for (int o = 32; o > 0; o >>= 1) v += __shfl_down(v, o);
    int lane = threadIdx.x & 63, wid = threadIdx.x >> 6;
    __syncthreads();
    if (lane == 0) s_red[wid] = v;
    __syncthreads();
    float t = 0.0f;
    if (threadIdx.x == 0)
        for (int w = 0; w < BLOCK / 64; ++w) t += s_red[w];
    return t;  // valid on thread 0 only
}

__global__ __launch_bounds__(BLOCK) void main_loss_kernel(
        const float* __restrict__ emb, const float* __restrict__ margins,
        const float* __restrict__ seed, const int* __restrict__ labels,
        int n, const float* __restrict__ P, float* __restrict__ pb) {
    __shared__ float4 s_par[NCLUS];  // ax,ay,az,b
    __shared__ float s_w[NCLUS];
    __shared__ float s_sig[NCLUS];
    __shared__ float s_red[BLOCK / 64];

    if (threadIdx.x < NCLUS) {
        s_par[threadIdx.x] = ((const float4*)P)[threadIdx.x];
        s_w[threadIdx.x] = P[256 + threadIdx.x];
        s_sig[threadIdx.x] = P[320 + threadIdx.x];
    }
    __syncthreads();

    const int chunks = n >> 2;
    const int npairs = chunks >> 1;  // 8 points per pair
    const int stride = gridDim.x * blockDim.x;
    const float4* e4 = (const float4*)emb;
    const float4* m4 = (const float4*)margins;
    const float4* s4 = (const float4*)seed;
    const int4* l4 = (const int4*)labels;

    float bce = 0.0f, seed_s = 0.0f, smooth_s = 0.0f;

    for (int pi = blockIdx.x * blockDim.x + threadIdx.x; pi < npairs; pi += stride) {
        int ch0 = pi * 2;
        float x[8], y[8], z[8], es[8], a[8];
#pragma unroll
        for (int h = 0; h < 2; ++h) {
            float4 e0 = e4[(ch0 + h) * 3 + 0];
            float4 e1 = e4[(ch0 + h) * 3 + 1];
            float4 e2 = e4[(ch0 + h) * 3 + 2];
            x[h * 4 + 0] = e0.x; y[h * 4 + 0] = e0.y; z[h * 4 + 0] = e0.z;
            x[h * 4 + 1] = e0.w; y[h * 4 + 1] = e1.x; z[h * 4 + 1] = e1.y;
            x[h * 4 + 2] = e1.z; y[h * 4 + 2] = e1.w; z[h * 4 + 2] = e2.x;
            x[h * 4 + 3] = e2.y; y[h * 4 + 3] = e2.z; z[h * 4 + 3] = e2.w;
        }
#pragma unroll
        for (int k = 0; k < 8; ++k) {
            es[k] = fmaf(x[k], x[k], fmaf(y[k], y[k], z[k] * z[k]));
            a[k] = 0.0f;
        }

#pragma unroll 4
        for (int c = 0; c < NCLUS; ++c) {
            float4 pr = s_par[c];
            float w2 = s_w[c];
#pragma unroll
            for (int k = 0; k < 8; ++k) {
                float t = fmaf(pr.x, x[k],
                          fmaf(pr.y, y[k],
                          fmaf(pr.z, z[k],
                          fmaf(w2, es[k], pr.w))));
                float p = EXP2F(t);
                float X = fmaf(p, fmaf(p, fmaf(p, SP_C4, SP_C3), SP_C2), SP_C1);
                a[k] = fmaf(p, X, a[k]);
            }
        }
        bce += ((a[0] + a[1]) + (a[2] + a[3])) + ((a[4] + a[5]) + (a[6] + a[7]));

        float4 mg0 = m4[ch0], mg1 = m4[ch0 + 1];
        float4 sd0 = s4[ch0], sd1 = s4[ch0 + 1];
        int4 lb0 = l4[ch0], lb1 = l4[ch0 + 1];
        float m[8] = {mg0.x, mg0.y, mg0.z, mg0.w, mg1.x, mg1.y, mg1.z, mg1.w};
        float s[8] = {sd0.x, sd0.y, sd0.z, sd0.w, sd1.x, sd1.y, sd1.z, sd1.w};
        int   l[8] = {lb0.x, lb0.y, lb0.z, lb0.w, lb1.x, lb1.y, lb1.z, lb1.w};
#pragma unroll
        for (int k = 0; k < 8; ++k) {
            float4 pr = s_par[l[k]];
            float w2 = s_w[l[k]];
            float t = fmaf(pr.x, x[k],
                      fmaf(pr.y, y[k],
                      fmaf(pr.z, z[k],
                      fmaf(w2, es[k], pr.w))));
            float p = EXP2F(t);
            bce -= p;
            seed_s += fabsf(p - s[k]);
            float dsg = m[k] - s_sig[l[k]];
            smooth_s += dsg * dsg;
        }
    }

    // scalar tail
    int covered = npairs * 8;
    int rem = n - covered;
    int gid = blockIdx.x * blockDim.x + threadIdx.x;
    if (gid < rem) {
        int i = covered + gid;
        float ex = emb[i * 3 + 0], ey = emb[i * 3 + 1], ez = emb[i * 3 + 2];
        float esq = fmaf(ex, ex, fmaf(ey, ey, ez * ez));
        int lab = labels[i];
        float pl = 0.0f;
        for (int c = 0; c < NCLUS; ++c) {
            float4 pr = s_par[c];
            float w2 = s_w[c];
            float t = fmaf(pr.x, ex, fmaf(pr.y, ey, fmaf(pr.z, ez, fmaf(w2, esq, pr.w))));
            float p = EXP2F(t);
            float X = fmaf(p, fmaf(p, fmaf(p, SP_C4, SP_C3), SP_C2), SP_C1);
            bce = fmaf(p, X, bce);
            if (c == lab) pl = p;
        }
        bce -= pl;
        seed_s += fabsf(pl - seed[i]);
        float dsg = margins[i] - s_sig[lab];
        smooth_s += dsg * dsg;
    }

    float r;
    r = block_reduce_sum(bce, s_red);
    if (threadIdx.x == 0) pb[blockIdx.x * 3 + 0] = r;
    r = block_reduce_sum(seed_s, s_red);
    if (threadIdx.x == 0) pb[blockIdx.x * 3 + 1] = r;
    r = block_reduce_sum(smooth_s, s_red);
    if (threadIdx.x == 0) pb[blockIdx.x * 3 + 2] = r;
}

// one wave; GM must equal 64*8
__global__ void finalize_kernel(const float* __restrict__ pb,
                                float* __restrict__ out, int n) {
    int lane = threadIdx.x;
    double sums[3];
#pragma unroll
    for (int k = 0; k < 3; ++k) {
        double v = 0.0;
#pragma unroll
        for (int j = 0; j < 8; ++j)
            v += (double)pb[(lane * 8 + j) * 3 + k];
        for (int o = 32; o > 0; o >>= 1) v += __shfl_down(v, o);
        sums[k] = v;
    }
    if (lane == 0) {
        double bce_total = sums[0] + (double)n * 64.0 * SP_C0;
        double mask_loss = bce_total / ((double)NCLUS * (double)n);
        double seed_loss = sums[1] / (double)n;
        double smooth_loss = sums[2] / (double)NCLUS;
        out[0] = (float)(mask_loss + seed_loss + smooth_loss);
    }
}

extern "C" void kernel_launch(void* const* d_in, const int* in_sizes, int n_in,
                              void* d_out, int out_size, void* d_ws, size_t ws_size,
                              hipStream_t stream) {
    const float* emb     = (const float*)d_in[0];
    const float* margins = (const float*)d_in[1];
    const float* seed    = (const float*)d_in[2];
    const float* coords  = (const float*)d_in[3];
    const int*   labels  = (const int*)d_in[4];
    int n = in_sizes[4];

    unsigned long long* S = (unsigned long long*)d_ws;
    float* P  = (float*)((char*)d_ws + 2560);
    float* pb = (float*)((char*)d_ws + 4096);
    float* out = (float*)d_out;

    init_ws_kernel<<<1, 5 * NCLUS, 0, stream>>>(S);
    cluster_sums_kernel<<<GC, BLOCK, 0, stream>>>(coords, margins, labels, n, S);
    compute_params_kernel<<<1, 64, 0, stream>>>(S, P);
    main_loss_kernel<<<GM, BLOCK, 0, stream>>>(emb, margins, seed, labels, n, P, pb);
    finalize_kernel<<<1, 64, 0, stream>>>(pb, out, n);
}